// Round 2
// 171.180 us; speedup vs baseline: 1.0569x; 1.0569x over previous
//
#include <hip/hip_runtime.h>
#include <math.h>

// Problem constants (B=8, H=8, N=2048, C=64). fp32 inputs/outputs.
// Q staged in d_ws as bf16 PRE-SCALED by C^-0.5 * log2(e) (flash uses exp2 =
// bare v_exp_f32). K natural [head][n][c]; V transposed Vt[head][c][n].
// Round 10 (resubmit after infra failure): flash at 512 threads = 8 waves
// (tm=2 per wave), TQ=256, grid 512 -> 2 blocks/CU -> 16 waves/CU (was 8).
// Staging split: waves 0-3 stage K, waves 4-7 stage Vt (1 glds16/thread).
// Softmax P-pack uses v_cvt_pk_bf16_f32 (1 inst) instead of 5-op bit math.
// Proj kernel unchanged from round 9.
#define BH    64
#define NSEQ  2048
#define CDIM  64
#define WSTR  72   // proj Wb row stride in u16

typedef unsigned short ushort_t;
typedef __attribute__((ext_vector_type(8))) short short8;    // 8 bf16 (4 VGPR)
typedef __attribute__((ext_vector_type(4))) float float4v;   // mfma C/D

// fp32 -> bf16 bits, round-to-nearest-even
__device__ __forceinline__ ushort_t f32_to_bf16_rne(float x) {
  unsigned int u = __float_as_uint(x);
  u += 0x7fffu + ((u >> 16) & 1u);
  return (ushort_t)(u >> 16);
}

// pack 2 f32 -> 2 bf16 in a u32 (round-half-up) -- proj only
__device__ __forceinline__ unsigned int pk2(float a, float b) {
  return ((__float_as_uint(a) + 0x8000u) >> 16) |
         ((__float_as_uint(b) + 0x8000u) & 0xffff0000u);
}

// pack 2 f32 -> 2 bf16 in a u32, single HW instruction (RNE)
__device__ __forceinline__ unsigned int cvtpk(float a, float b) {
  unsigned int r;
  asm("v_cvt_pk_bf16_f32 %0, %1, %2" : "=v"(r) : "v"(a), "v"(b));
  return r;
}

// async global->LDS, 16B per lane; LDS dest = wave-uniform base + lane*16
__device__ __forceinline__ void glds16(const ushort_t* g, ushort_t* l) {
  __builtin_amdgcn_global_load_lds(
      (const __attribute__((address_space(1))) void*)g,
      (__attribute__((address_space(3))) void*)l, 16, 0, 0);
}

// ---------------- QKV projection (MFMA, packed b64 stores) ----------------
// qkv[row, d] = sum_c x[row, c] * W[d, c];  d<64 -> Q (x 0.125*log2e), <128 -> K, else V.
// Q/K: acc = mfma(wf, xf)  -> lane holds 4 consecutive d for fixed row -> b64.
// V:   acc = mfma(xf, wf)  -> lane holds 4 consecutive rows (n) for fixed c
//      -> b64 straight into Vt[head][c][n] (transpose for free).
__global__ __launch_bounds__(256) void qkv_proj_mfma(
    const float* __restrict__ x, const float* __restrict__ w,
    ushort_t* __restrict__ q, ushort_t* __restrict__ k,
    ushort_t* __restrict__ vt) {
  __shared__ ushort_t Wb[192 * WSTR];   // 27648 B
  const int t = threadIdx.x;
  const int lane = t & 63, wv = t >> 6;
  const int quad = lane >> 4, l16 = lane & 15;
  const long rowbase = (long)blockIdx.x * 128;
  const int head  = (int)(rowbase >> 11);
  const int nbase = (int)(rowbase & 2047);

  // stage W as bf16; Q-rows (d<64) pre-scaled by 0.125*log2(e)
  for (int u = t; u < 1536; u += 256) {
    const int d = u >> 3, o8 = (u & 7) * 8;
    const float sc = (d < 64) ? 0.1803368801111244f : 1.0f;  // 0.125*log2(e)
    const float4 f0 = *reinterpret_cast<const float4*>(w + d * 64 + o8);
    const float4 f1 = *reinterpret_cast<const float4*>(w + d * 64 + o8 + 4);
    ushort_t tmp[8] __attribute__((aligned(16)));
    tmp[0] = f32_to_bf16_rne(f0.x * sc); tmp[1] = f32_to_bf16_rne(f0.y * sc);
    tmp[2] = f32_to_bf16_rne(f0.z * sc); tmp[3] = f32_to_bf16_rne(f0.w * sc);
    tmp[4] = f32_to_bf16_rne(f1.x * sc); tmp[5] = f32_to_bf16_rne(f1.y * sc);
    tmp[6] = f32_to_bf16_rne(f1.z * sc); tmp[7] = f32_to_bf16_rne(f1.w * sc);
    *reinterpret_cast<uint4*>(&Wb[d * WSTR + o8]) = *reinterpret_cast<const uint4*>(tmp);
  }
  __syncthreads();

  // A/B x-frags: x rows, converted to bf16
  short8 xf[2][2];
#pragma unroll
  for (int tm = 0; tm < 2; ++tm)
#pragma unroll
    for (int kb = 0; kb < 2; ++kb) {
      const float* xp = x + (rowbase + wv * 32 + tm * 16 + l16) * 64 + kb * 32 + quad * 8;
      const float4 f0 = *reinterpret_cast<const float4*>(xp);
      const float4 f1 = *reinterpret_cast<const float4*>(xp + 4);
      ushort_t tmp[8] __attribute__((aligned(16)));
      tmp[0] = f32_to_bf16_rne(f0.x); tmp[1] = f32_to_bf16_rne(f0.y);
      tmp[2] = f32_to_bf16_rne(f0.z); tmp[3] = f32_to_bf16_rne(f0.w);
      tmp[4] = f32_to_bf16_rne(f1.x); tmp[5] = f32_to_bf16_rne(f1.y);
      tmp[6] = f32_to_bf16_rne(f1.z); tmp[7] = f32_to_bf16_rne(f1.w);
      xf[tm][kb] = *reinterpret_cast<const short8*>(tmp);
    }

  float4v aqk[8][2];   // [d-tile][x-tile], swapped: D[d][row]
  float4v av[2][4];    // [x-tile][d-tile], normal: D[row][c]
#pragma unroll
  for (int nt = 0; nt < 8; ++nt)
#pragma unroll
    for (int tm = 0; tm < 2; ++tm)
#pragma unroll
      for (int r = 0; r < 4; ++r) aqk[nt][tm][r] = 0.f;
#pragma unroll
  for (int tm = 0; tm < 2; ++tm)
#pragma unroll
    for (int nt = 0; nt < 4; ++nt)
#pragma unroll
      for (int r = 0; r < 4; ++r) av[tm][nt][r] = 0.f;

#pragma unroll
  for (int kb = 0; kb < 2; ++kb) {
#pragma unroll
    for (int nt = 0; nt < 8; ++nt) {
      const short8 wf = *reinterpret_cast<const short8*>(
          &Wb[(nt * 16 + l16) * WSTR + kb * 32 + quad * 8]);
      aqk[nt][0] = __builtin_amdgcn_mfma_f32_16x16x32_bf16(wf, xf[0][kb], aqk[nt][0], 0, 0, 0);
      aqk[nt][1] = __builtin_amdgcn_mfma_f32_16x16x32_bf16(wf, xf[1][kb], aqk[nt][1], 0, 0, 0);
    }
#pragma unroll
    for (int nt = 0; nt < 4; ++nt) {
      const short8 wfv = *reinterpret_cast<const short8*>(
          &Wb[((128 + nt * 16) + l16) * WSTR + kb * 32 + quad * 8]);
      av[0][nt] = __builtin_amdgcn_mfma_f32_16x16x32_bf16(xf[0][kb], wfv, av[0][nt], 0, 0, 0);
      av[1][nt] = __builtin_amdgcn_mfma_f32_16x16x32_bf16(xf[1][kb], wfv, av[1][nt], 0, 0, 0);
    }
  }

  // Q/K stores: row = rowbase + wv*32+tm*16+l16, d = nt*16 + quad*4 + r
#pragma unroll
  for (int tm = 0; tm < 2; ++tm) {
    const long row = rowbase + wv * 32 + tm * 16 + l16;
#pragma unroll
    for (int nt = 0; nt < 8; ++nt) {
      uint2 pk;
      pk.x = pk2(aqk[nt][tm][0], aqk[nt][tm][1]);
      pk.y = pk2(aqk[nt][tm][2], aqk[nt][tm][3]);
      if (nt < 4)
        *reinterpret_cast<uint2*>(q + row * 64 + nt * 16 + quad * 4) = pk;
      else
        *reinterpret_cast<uint2*>(k + row * 64 + (nt - 4) * 16 + quad * 4) = pk;
    }
  }
  // V stores: c = nt*16 + l16, n = nbase + wv*32+tm*16+quad*4 + r
#pragma unroll
  for (int tm = 0; tm < 2; ++tm)
#pragma unroll
    for (int nt = 0; nt < 4; ++nt) {
      const int c = nt * 16 + l16;
      uint2 pk;
      pk.x = pk2(av[tm][nt][0], av[tm][nt][1]);
      pk.y = pk2(av[tm][nt][2], av[tm][nt][3]);
      *reinterpret_cast<uint2*>(vt + (long)head * (64 * 2048) + (long)c * 2048 +
                                nbase + wv * 32 + tm * 16 + quad * 4) = pk;
    }
}

// ---------------- MFMA flash attention (transposed dataflow, TQ=256) --------
// block: 512 threads = 8 waves, 32 q-rows per wave (tm=2). TK=32. grid 512
// (2 blocks/CU -> 16 waves/CU), XCD swizzle: bh = (id&7)*8 + (id>>3)&7,
// qt = id>>6.
// LDS (all XOR-swizzled, chunk = 8 u16 = 16B):
//   Ks2[2][32*64]: K tile [kv][c],  chunk' = chunk ^ (row&7)      (8 chunks/row)
//   Vs2[2][64*32]: Vt tile [c][kv], chunk' = chunk ^ ((row>>1)&3) (4 chunks/row)
//   Ps  [256*32]:  P [qrow][kv],    chunk' = chunk ^ ((row>>1)&3)
// Staging split: waves 0-3 stage K (8 rows each), waves 4-7 stage Vt
// (16 c-rows each) -- one glds16 per thread per tile.
// mfma_f32_16x16x32_bf16: A/B lane map op[idx=lane&15][k=quad*8+j];
// C/D: reg r = D[row=quad*4+r][col=lane&15].
// S^T = mfma(kf, qf): reg r = S[qrow=tm*16+l16][kv=nt*16+quad*4+r] -> b64 pack.
// O^T = mfma(vf, pf): reg r = O[qrow=tm*16+l16][c=ct*16+quad*4+r] -> float4 out.
__global__ __launch_bounds__(512, 4) void flash_attn_mfma(
    const ushort_t* __restrict__ q, const ushort_t* __restrict__ k,
    const ushort_t* __restrict__ vt, float* __restrict__ out) {
  __shared__ ushort_t Ks2[2][32 * 64];  // 8 KB
  __shared__ ushort_t Vs2[2][64 * 32];  // 8 KB
  __shared__ ushort_t Ps[256 * 32];     // 16 KB, per-wave 32-row slices
  const int t = threadIdx.x;
  const int lane = t & 63, w = t >> 6;           // w = 0..7
  const int quad = lane >> 4, l16 = lane & 15;
  const int id = blockIdx.x;
  const int qt = id >> 6;
  const int bh = ((id & 7) << 3) | ((id >> 3) & 7);   // XCD-clustered heads
  const long hoff = (long)bh * NSEQ * CDIM;
  const ushort_t* qp  = q  + hoff + (long)qt * 256 * CDIM;
  const ushort_t* kp  = k  + hoff;
  const ushort_t* vtp = vt + hoff;     // [64][2048]

  // Q frags (pre-scaled), loaded once: B operand, Q[qrow=w*32+tm*16+l16][k]
  short8 qf[2][2];
#pragma unroll
  for (int tm = 0; tm < 2; ++tm)
#pragma unroll
    for (int kb = 0; kb < 2; ++kb)
      qf[tm][kb] = *reinterpret_cast<const short8*>(
          qp + (w * 32 + tm * 16 + l16) * 64 + kb * 32 + quad * 8);

  float4v O[4][2];   // [c-tile][q-tile]
  float rs[2];
  rs[0] = 0.f; rs[1] = 0.f;
#pragma unroll
  for (int ct = 0; ct < 4; ++ct)
#pragma unroll
    for (int tm = 0; tm < 2; ++tm)
#pragma unroll
      for (int r = 0; r < 4; ++r) O[ct][tm][r] = 0.f;

  // staging constants (per lane); waves 0-3 stage K, waves 4-7 stage Vt
  const int ws = w & 3;
  const bool isK = (w < 4);
  const int krow = ws * 8 + (lane >> 3);         // K: 8 rows/wave
  const int kchk = (lane & 7) ^ (lane >> 3);     // ^ (row & 7)
  const int kdst = ws * 8 * 64;                  // u16
  const int vrow = ws * 16 + (lane >> 2);        // V: 16 c-rows/wave
  const int vchk = (lane & 3) ^ ((lane >> 3) & 3);  // ^ ((row>>1) & 3)
  const int vdst = ws * 16 * 32;                 // u16
  const int pswz = (l16 >> 1) & 3;               // Ps/Vs read swizzle term

  // prologue: stage tile 0 into buffer 0
  if (isK) glds16(kp + (long)krow * 64 + kchk * 8, &Ks2[0][kdst]);
  else     glds16(vtp + (long)vrow * 2048 + vchk * 8, &Vs2[0][vdst]);

  for (int tile = 0; tile < NSEQ / 32; ++tile) {
    const int cur = tile & 1;
    __syncthreads();   // implicit vmcnt(0): buf[cur] ready; buf[1-cur] free
    if (tile < NSEQ / 32 - 1) {
      const long nxt = tile + 1;
      if (isK) glds16(kp + (nxt * 32 + krow) * 64 + kchk * 8, &Ks2[1 - cur][kdst]);
      else     glds16(vtp + (long)vrow * 2048 + nxt * 32 + vchk * 8, &Vs2[1 - cur][vdst]);
    }

    // S^T = K Q^T  (2 kv-tiles x 2 q-tiles of 16x16 per wave)
    float4v s[2][2];
#pragma unroll
    for (int nt = 0; nt < 2; ++nt)
#pragma unroll
      for (int tm = 0; tm < 2; ++tm)
#pragma unroll
        for (int r = 0; r < 4; ++r) s[nt][tm][r] = 0.f;

#pragma unroll
    for (int kb = 0; kb < 2; ++kb) {
      short8 kf[2];   // A: K[kv=nt*16+l16][k=kb*32+quad*8+j]
#pragma unroll
      for (int nt = 0; nt < 2; ++nt)
        kf[nt] = *reinterpret_cast<const short8*>(
            &Ks2[cur][(nt * 16 + l16) * 64 + (((kb * 4 + quad) ^ (l16 & 7)) * 8)]);
#pragma unroll
      for (int nt = 0; nt < 2; ++nt)
#pragma unroll
        for (int tm = 0; tm < 2; ++tm)
          s[nt][tm] = __builtin_amdgcn_mfma_f32_16x16x32_bf16(
              kf[nt], qf[tm][kb], s[nt][tm], 0, 0, 0);
    }

    // p = exp2(s'); lane-private partial sums; b64 pack into Ps[qrow][kv]
#pragma unroll
    for (int tm = 0; tm < 2; ++tm)
#pragma unroll
      for (int nt = 0; nt < 2; ++nt) {
        const float p0 = __builtin_amdgcn_exp2f(s[nt][tm][0]);
        const float p1 = __builtin_amdgcn_exp2f(s[nt][tm][1]);
        const float p2 = __builtin_amdgcn_exp2f(s[nt][tm][2]);
        const float p3 = __builtin_amdgcn_exp2f(s[nt][tm][3]);
        rs[tm] += (p0 + p1) + (p2 + p3);
        uint2 pk;
        pk.x = cvtpk(p0, p1);
        pk.y = cvtpk(p2, p3);
        *reinterpret_cast<uint2*>(
            &Ps[(w * 32 + tm * 16 + l16) * 32 +
                (((nt * 2 + (quad >> 1)) ^ pswz) * 8) + (quad & 1) * 4]) = pk;
      }

    // O^T += Vt P^T  (wave-private Ps slice -> no barrier; k-depth = 32)
    {
      short8 pf[2], vf[4];
#pragma unroll
      for (int tm = 0; tm < 2; ++tm)
        pf[tm] = *reinterpret_cast<const short8*>(
            &Ps[(w * 32 + tm * 16 + l16) * 32 + ((quad ^ pswz) * 8)]);
#pragma unroll
      for (int ct = 0; ct < 4; ++ct)
        vf[ct] = *reinterpret_cast<const short8*>(
            &Vs2[cur][(ct * 16 + l16) * 32 + ((quad ^ pswz) * 8)]);
#pragma unroll
      for (int ct = 0; ct < 4; ++ct)
#pragma unroll
        for (int tm = 0; tm < 2; ++tm)
          O[ct][tm] = __builtin_amdgcn_mfma_f32_16x16x32_bf16(
              vf[ct], pf[tm], O[ct][tm], 0, 0, 0);
    }
  }

  // epilogue: quad-reduce row sums, normalize, head-mix shuffle, float4 out
  // final[b, h2, n, h*8+c2] = out_head[b, h, n, h2*8+c2]
  const int bi = bh >> 3, h = bh & 7;
  float inv[2];
#pragma unroll
  for (int tm = 0; tm < 2; ++tm) {
    float l = rs[tm];
    l += __shfl_xor(l, 16, 64);
    l += __shfl_xor(l, 32, 64);
    inv[tm] = 1.f / l;
  }
#pragma unroll
  for (int ct = 0; ct < 4; ++ct)
#pragma unroll
    for (int tm = 0; tm < 2; ++tm) {
      const int n = qt * 256 + w * 32 + tm * 16 + l16;
      const int h2 = ct * 2 + (quad >> 1);          // (ct*16+quad*4)>>3
      const int c2b = (quad & 1) * 4;
      float4 v4;
      v4.x = O[ct][tm][0] * inv[tm]; v4.y = O[ct][tm][1] * inv[tm];
      v4.z = O[ct][tm][2] * inv[tm]; v4.w = O[ct][tm][3] * inv[tm];
      *reinterpret_cast<float4*>(
          &out[(((long)(bi * 8 + h2)) * NSEQ + n) * 64 + h * 8 + c2b]) = v4;
    }
}

extern "C" void kernel_launch(void* const* d_in, const int* in_sizes, int n_in,
                              void* d_out, int out_size, void* d_ws, size_t ws_size,
                              hipStream_t stream) {
  (void)in_sizes; (void)n_in; (void)out_size; (void)ws_size;
  const float* x = (const float*)d_in[0];   // [8,8,2048,64] fp32
  const float* w = (const float*)d_in[1];   // [192,64] fp32
  float* out = (float*)d_out;               // [8,8,2048,64] fp32

  // workspace: Q(scaled),K natural + Vt transposed, bf16 bits, 16.78 MB each
  ushort_t* qws  = (ushort_t*)d_ws;
  ushort_t* kws  = qws + (size_t)BH * NSEQ * CDIM;
  ushort_t* vtws = kws + (size_t)BH * NSEQ * CDIM;

  qkv_proj_mfma<<<(BH * NSEQ) / 128, 256, 0, stream>>>(x, w, qws, kws, vtws);
  flash_attn_mfma<<<512, 512, 0, stream>>>(qws, kws, vtws, out);
}

// Round 4
// 164.451 us; speedup vs baseline: 1.1002x; 1.0409x over previous
//
#include <hip/hip_runtime.h>
#include <math.h>

// Problem constants (B=8, H=8, N=2048, C=64). fp32 inputs/outputs.
// Q staged in d_ws as bf16 PRE-SCALED by C^-0.5 * log2(e) (flash uses exp2 =
// bare v_exp_f32). K natural [head][n][c]; V transposed Vt[head][c][n].
// Round 12: revert the wimg/w_prep path (suspected ws overflow -> NaN).
// W conversion back in-kernel (round-2 known-good staging, WSTR=72).
// KEPT from round 11: LDS-gather epilogue -- accumulators packed into a
// swizzled LDS buffer (overlaid on Wb after MFMA), read back linearly,
// stored as fully-coalesced uint4 (was 24 scattered 8B stores/thread).
// Flash unchanged from round 10 (85.4 us, Occ 34%). Workspace back to
// exactly 3 bf16 arrays (50.33 MB).
#define BH    64
#define NSEQ  2048
#define CDIM  64
#define WSTR  72   // proj Wb row stride in u16

typedef unsigned short ushort_t;
typedef __attribute__((ext_vector_type(8))) short short8;    // 8 bf16 (4 VGPR)
typedef __attribute__((ext_vector_type(4))) float float4v;   // mfma C/D

// fp32 -> bf16 bits, round-to-nearest-even
__device__ __forceinline__ ushort_t f32_to_bf16_rne(float x) {
  unsigned int u = __float_as_uint(x);
  u += 0x7fffu + ((u >> 16) & 1u);
  return (ushort_t)(u >> 16);
}

// pack 2 f32 -> 2 bf16 in a u32, single HW instruction (RNE)
__device__ __forceinline__ unsigned int cvtpk(float a, float b) {
  unsigned int r;
  asm("v_cvt_pk_bf16_f32 %0, %1, %2" : "=v"(r) : "v"(a), "v"(b));
  return r;
}

// async global->LDS, 16B per lane; LDS dest = wave-uniform base + lane*16
__device__ __forceinline__ void glds16(const ushort_t* g, ushort_t* l) {
  __builtin_amdgcn_global_load_lds(
      (const __attribute__((address_space(1))) void*)g,
      (__attribute__((address_space(3))) void*)l, 16, 0, 0);
}

// ---------------- QKV projection (MFMA, LDS-gathered coalesced stores) ----
// qkv[row, d] = sum_c x[row, c] * W[d, c];  d<64 -> Q (x 0.125*log2e), <128 ->
// K, else V.  Q/K: acc = mfma(wf, xf) -> D[d][row]; V: acc = mfma(xf, wf) ->
// D[row][c] (free transpose for Vt).  Epilogue: pack accs into swizzled LDS
// (overlaid on Wb), read back linearly, store coalesced uint4.
__global__ __launch_bounds__(256) void qkv_proj_mfma(
    const float* __restrict__ x, const float* __restrict__ w,
    ushort_t* __restrict__ q, ushort_t* __restrict__ k,
    ushort_t* __restrict__ vt) {
  __shared__ ushort_t Wb[192 * WSTR];   // 27648 B; reused as gather buffer
  ushort_t* Sg = Wb;                    // overlay (16384 B needed)
  const int t = threadIdx.x;
  const int lane = t & 63, wv = t >> 6;
  const int quad = lane >> 4, l16 = lane & 15;
  const long rowbase = (long)blockIdx.x * 128;
  const int head  = (int)(rowbase >> 11);
  const int nbase = (int)(rowbase & 2047);

  // stage W as bf16; Q-rows (d<64) pre-scaled by 0.125*log2(e)
  for (int u = t; u < 1536; u += 256) {
    const int d = u >> 3, o8 = (u & 7) * 8;
    const float sc = (d < 64) ? 0.1803368801111244f : 1.0f;  // 0.125*log2(e)
    const float4 f0 = *reinterpret_cast<const float4*>(w + d * 64 + o8);
    const float4 f1 = *reinterpret_cast<const float4*>(w + d * 64 + o8 + 4);
    ushort_t tmp[8] __attribute__((aligned(16)));
    tmp[0] = f32_to_bf16_rne(f0.x * sc); tmp[1] = f32_to_bf16_rne(f0.y * sc);
    tmp[2] = f32_to_bf16_rne(f0.z * sc); tmp[3] = f32_to_bf16_rne(f0.w * sc);
    tmp[4] = f32_to_bf16_rne(f1.x * sc); tmp[5] = f32_to_bf16_rne(f1.y * sc);
    tmp[6] = f32_to_bf16_rne(f1.z * sc); tmp[7] = f32_to_bf16_rne(f1.w * sc);
    *reinterpret_cast<uint4*>(&Wb[d * WSTR + o8]) = *reinterpret_cast<const uint4*>(tmp);
  }
  __syncthreads();

  // A/B x-frags: x rows, converted to bf16
  short8 xf[2][2];
#pragma unroll
  for (int tm = 0; tm < 2; ++tm)
#pragma unroll
    for (int kb = 0; kb < 2; ++kb) {
      const float* xp = x + (rowbase + wv * 32 + tm * 16 + l16) * 64 + kb * 32 + quad * 8;
      const float4 f0 = *reinterpret_cast<const float4*>(xp);
      const float4 f1 = *reinterpret_cast<const float4*>(xp + 4);
      ushort_t tmp[8] __attribute__((aligned(16)));
      tmp[0] = f32_to_bf16_rne(f0.x); tmp[1] = f32_to_bf16_rne(f0.y);
      tmp[2] = f32_to_bf16_rne(f0.z); tmp[3] = f32_to_bf16_rne(f0.w);
      tmp[4] = f32_to_bf16_rne(f1.x); tmp[5] = f32_to_bf16_rne(f1.y);
      tmp[6] = f32_to_bf16_rne(f1.z); tmp[7] = f32_to_bf16_rne(f1.w);
      xf[tm][kb] = *reinterpret_cast<const short8*>(tmp);
    }

  float4v aqk[8][2];   // [d-tile][x-tile], swapped: D[d][row]
  float4v av[2][4];    // [x-tile][d-tile], normal: D[row][c]
#pragma unroll
  for (int nt = 0; nt < 8; ++nt)
#pragma unroll
    for (int tm = 0; tm < 2; ++tm)
#pragma unroll
      for (int r = 0; r < 4; ++r) aqk[nt][tm][r] = 0.f;
#pragma unroll
  for (int tm = 0; tm < 2; ++tm)
#pragma unroll
    for (int nt = 0; nt < 4; ++nt)
#pragma unroll
      for (int r = 0; r < 4; ++r) av[tm][nt][r] = 0.f;

#pragma unroll
  for (int kb = 0; kb < 2; ++kb) {
#pragma unroll
    for (int nt = 0; nt < 8; ++nt) {
      const short8 wf = *reinterpret_cast<const short8*>(
          &Wb[(nt * 16 + l16) * WSTR + kb * 32 + quad * 8]);
      aqk[nt][0] = __builtin_amdgcn_mfma_f32_16x16x32_bf16(wf, xf[0][kb], aqk[nt][0], 0, 0, 0);
      aqk[nt][1] = __builtin_amdgcn_mfma_f32_16x16x32_bf16(wf, xf[1][kb], aqk[nt][1], 0, 0, 0);
    }
#pragma unroll
    for (int nt = 0; nt < 4; ++nt) {
      const short8 wfv = *reinterpret_cast<const short8*>(
          &Wb[((128 + nt * 16) + l16) * WSTR + kb * 32 + quad * 8]);
      av[0][nt] = __builtin_amdgcn_mfma_f32_16x16x32_bf16(xf[0][kb], wfv, av[0][nt], 0, 0, 0);
      av[1][nt] = __builtin_amdgcn_mfma_f32_16x16x32_bf16(xf[1][kb], wfv, av[1][nt], 0, 0, 0);
    }
  }

  __syncthreads();   // all MFMA reads of Wb done -> safe to reuse as Sg

  // ---- Q section: gather into Sg[row][d] (chunk ^= row&7), store coalesced
#pragma unroll
  for (int tm = 0; tm < 2; ++tm) {
    const int row = wv * 32 + tm * 16 + l16;
#pragma unroll
    for (int nt = 0; nt < 4; ++nt) {
      const int dchunk = nt * 2 + (quad >> 1);
      uint2 pk;
      pk.x = cvtpk(aqk[nt][tm][0], aqk[nt][tm][1]);
      pk.y = cvtpk(aqk[nt][tm][2], aqk[nt][tm][3]);
      *reinterpret_cast<uint2*>(
          &Sg[row * 64 + ((dchunk ^ (row & 7)) * 8) + (quad & 1) * 4]) = pk;
    }
  }
  __syncthreads();
#pragma unroll
  for (int i = 0; i < 4; ++i) {
    const int g = i * 256 + t;           // 1024 chunks = 128 rows x 8
    const int row = g >> 3, ch = g & 7;
    const uint4 v = *reinterpret_cast<const uint4*>(
        &Sg[row * 64 + ((ch ^ (row & 7)) * 8)]);
    *reinterpret_cast<uint4*>(q + (rowbase + row) * 64 + ch * 8) = v;
  }
  __syncthreads();

  // ---- K section (reuse Sg)
#pragma unroll
  for (int tm = 0; tm < 2; ++tm) {
    const int row = wv * 32 + tm * 16 + l16;
#pragma unroll
    for (int nt = 4; nt < 8; ++nt) {
      const int dchunk = (nt - 4) * 2 + (quad >> 1);
      uint2 pk;
      pk.x = cvtpk(aqk[nt][tm][0], aqk[nt][tm][1]);
      pk.y = cvtpk(aqk[nt][tm][2], aqk[nt][tm][3]);
      *reinterpret_cast<uint2*>(
          &Sg[row * 64 + ((dchunk ^ (row & 7)) * 8) + (quad & 1) * 4]) = pk;
    }
  }
  __syncthreads();
#pragma unroll
  for (int i = 0; i < 4; ++i) {
    const int g = i * 256 + t;
    const int row = g >> 3, ch = g & 7;
    const uint4 v = *reinterpret_cast<const uint4*>(
        &Sg[row * 64 + ((ch ^ (row & 7)) * 8)]);
    *reinterpret_cast<uint4*>(k + (rowbase + row) * 64 + ch * 8) = v;
  }
  __syncthreads();

  // ---- V section: Sg as [64][128] (Sv[c][n_local], chunk ^= c&15)
#pragma unroll
  for (int tm = 0; tm < 2; ++tm)
#pragma unroll
    for (int nt = 0; nt < 4; ++nt) {
      const int c = nt * 16 + l16;
      const int nchunk = wv * 4 + tm * 2 + (quad >> 1);
      uint2 pk;
      pk.x = cvtpk(av[tm][nt][0], av[tm][nt][1]);
      pk.y = cvtpk(av[tm][nt][2], av[tm][nt][3]);
      *reinterpret_cast<uint2*>(
          &Sg[c * 128 + ((nchunk ^ (c & 15)) * 8) + (quad & 1) * 4]) = pk;
    }
  __syncthreads();
#pragma unroll
  for (int i = 0; i < 4; ++i) {
    const int g = i * 256 + t;           // 1024 chunks = 64 c-rows x 16
    const int c = g >> 4, ch = g & 15;
    const uint4 v = *reinterpret_cast<const uint4*>(
        &Sg[c * 128 + ((ch ^ (c & 15)) * 8)]);
    *reinterpret_cast<uint4*>(vt + (long)head * (64 * 2048) + (long)c * 2048 +
                              nbase + ch * 8) = v;
  }
}

// ---------------- MFMA flash attention (transposed dataflow, TQ=256) --------
// block: 512 threads = 8 waves, 32 q-rows per wave (tm=2). TK=32. grid 512
// (2 blocks/CU -> 16 waves/CU), XCD swizzle: bh = (id&7)*8 + (id>>3)&7,
// qt = id>>6.
// LDS (all XOR-swizzled, chunk = 8 u16 = 16B):
//   Ks2[2][32*64]: K tile [kv][c],  chunk' = chunk ^ (row&7)      (8 chunks/row)
//   Vs2[2][64*32]: Vt tile [c][kv], chunk' = chunk ^ ((row>>1)&3) (4 chunks/row)
//   Ps  [256*32]:  P [qrow][kv],    chunk' = chunk ^ ((row>>1)&3)
// Staging split: waves 0-3 stage K (8 rows each), waves 4-7 stage Vt
// (16 c-rows each) -- one glds16 per thread per tile.
// mfma_f32_16x16x32_bf16: A/B lane map op[idx=lane&15][k=quad*8+j];
// C/D: reg r = D[row=quad*4+r][col=lane&15].
// S^T = mfma(kf, qf): reg r = S[qrow=tm*16+l16][kv=nt*16+quad*4+r] -> b64 pack.
// O^T = mfma(vf, pf): reg r = O[qrow=tm*16+l16][c=ct*16+quad*4+r] -> float4 out.
__global__ __launch_bounds__(512, 4) void flash_attn_mfma(
    const ushort_t* __restrict__ q, const ushort_t* __restrict__ k,
    const ushort_t* __restrict__ vt, float* __restrict__ out) {
  __shared__ ushort_t Ks2[2][32 * 64];  // 8 KB
  __shared__ ushort_t Vs2[2][64 * 32];  // 8 KB
  __shared__ ushort_t Ps[256 * 32];     // 16 KB, per-wave 32-row slices
  const int t = threadIdx.x;
  const int lane = t & 63, w = t >> 6;           // w = 0..7
  const int quad = lane >> 4, l16 = lane & 15;
  const int id = blockIdx.x;
  const int qt = id >> 6;
  const int bh = ((id & 7) << 3) | ((id >> 3) & 7);   // XCD-clustered heads
  const long hoff = (long)bh * NSEQ * CDIM;
  const ushort_t* qp  = q  + hoff + (long)qt * 256 * CDIM;
  const ushort_t* kp  = k  + hoff;
  const ushort_t* vtp = vt + hoff;     // [64][2048]

  // Q frags (pre-scaled), loaded once: B operand, Q[qrow=w*32+tm*16+l16][k]
  short8 qf[2][2];
#pragma unroll
  for (int tm = 0; tm < 2; ++tm)
#pragma unroll
    for (int kb = 0; kb < 2; ++kb)
      qf[tm][kb] = *reinterpret_cast<const short8*>(
          qp + (w * 32 + tm * 16 + l16) * 64 + kb * 32 + quad * 8);

  float4v O[4][2];   // [c-tile][q-tile]
  float rs[2];
  rs[0] = 0.f; rs[1] = 0.f;
#pragma unroll
  for (int ct = 0; ct < 4; ++ct)
#pragma unroll
    for (int tm = 0; tm < 2; ++tm)
#pragma unroll
      for (int r = 0; r < 4; ++r) O[ct][tm][r] = 0.f;

  // staging constants (per lane); waves 0-3 stage K, waves 4-7 stage Vt
  const int ws = w & 3;
  const bool isK = (w < 4);
  const int krow = ws * 8 + (lane >> 3);         // K: 8 rows/wave
  const int kchk = (lane & 7) ^ (lane >> 3);     // ^ (row & 7)
  const int kdst = ws * 8 * 64;                  // u16
  const int vrow = ws * 16 + (lane >> 2);        // V: 16 c-rows/wave
  const int vchk = (lane & 3) ^ ((lane >> 3) & 3);  // ^ ((row>>1) & 3)
  const int vdst = ws * 16 * 32;                 // u16
  const int pswz = (l16 >> 1) & 3;               // Ps/Vs read swizzle term

  // prologue: stage tile 0 into buffer 0
  if (isK) glds16(kp + (long)krow * 64 + kchk * 8, &Ks2[0][kdst]);
  else     glds16(vtp + (long)vrow * 2048 + vchk * 8, &Vs2[0][vdst]);

  for (int tile = 0; tile < NSEQ / 32; ++tile) {
    const int cur = tile & 1;
    __syncthreads();   // implicit vmcnt(0): buf[cur] ready; buf[1-cur] free
    if (tile < NSEQ / 32 - 1) {
      const long nxt = tile + 1;
      if (isK) glds16(kp + (nxt * 32 + krow) * 64 + kchk * 8, &Ks2[1 - cur][kdst]);
      else     glds16(vtp + (long)vrow * 2048 + nxt * 32 + vchk * 8, &Vs2[1 - cur][vdst]);
    }

    // S^T = K Q^T  (2 kv-tiles x 2 q-tiles of 16x16 per wave)
    float4v s[2][2];
#pragma unroll
    for (int nt = 0; nt < 2; ++nt)
#pragma unroll
      for (int tm = 0; tm < 2; ++tm)
#pragma unroll
        for (int r = 0; r < 4; ++r) s[nt][tm][r] = 0.f;

#pragma unroll
    for (int kb = 0; kb < 2; ++kb) {
      short8 kf[2];   // A: K[kv=nt*16+l16][k=kb*32+quad*8+j]
#pragma unroll
      for (int nt = 0; nt < 2; ++nt)
        kf[nt] = *reinterpret_cast<const short8*>(
            &Ks2[cur][(nt * 16 + l16) * 64 + (((kb * 4 + quad) ^ (l16 & 7)) * 8)]);
#pragma unroll
      for (int nt = 0; nt < 2; ++nt)
#pragma unroll
        for (int tm = 0; tm < 2; ++tm)
          s[nt][tm] = __builtin_amdgcn_mfma_f32_16x16x32_bf16(
              kf[nt], qf[tm][kb], s[nt][tm], 0, 0, 0);
    }

    // p = exp2(s'); lane-private partial sums; b64 pack into Ps[qrow][kv]
#pragma unroll
    for (int tm = 0; tm < 2; ++tm)
#pragma unroll
      for (int nt = 0; nt < 2; ++nt) {
        const float p0 = __builtin_amdgcn_exp2f(s[nt][tm][0]);
        const float p1 = __builtin_amdgcn_exp2f(s[nt][tm][1]);
        const float p2 = __builtin_amdgcn_exp2f(s[nt][tm][2]);
        const float p3 = __builtin_amdgcn_exp2f(s[nt][tm][3]);
        rs[tm] += (p0 + p1) + (p2 + p3);
        uint2 pk;
        pk.x = cvtpk(p0, p1);
        pk.y = cvtpk(p2, p3);
        *reinterpret_cast<uint2*>(
            &Ps[(w * 32 + tm * 16 + l16) * 32 +
                (((nt * 2 + (quad >> 1)) ^ pswz) * 8) + (quad & 1) * 4]) = pk;
      }

    // O^T += Vt P^T  (wave-private Ps slice -> no barrier; k-depth = 32)
    {
      short8 pf[2], vf[4];
#pragma unroll
      for (int tm = 0; tm < 2; ++tm)
        pf[tm] = *reinterpret_cast<const short8*>(
            &Ps[(w * 32 + tm * 16 + l16) * 32 + ((quad ^ pswz) * 8)]);
#pragma unroll
      for (int ct = 0; ct < 4; ++ct)
        vf[ct] = *reinterpret_cast<const short8*>(
            &Vs2[cur][(ct * 16 + l16) * 32 + ((quad ^ pswz) * 8)]);
#pragma unroll
      for (int ct = 0; ct < 4; ++ct)
#pragma unroll
        for (int tm = 0; tm < 2; ++tm)
          O[ct][tm] = __builtin_amdgcn_mfma_f32_16x16x32_bf16(
              vf[ct], pf[tm], O[ct][tm], 0, 0, 0);
    }
  }

  // epilogue: quad-reduce row sums, normalize, head-mix shuffle, float4 out
  // final[b, h2, n, h*8+c2] = out_head[b, h, n, h2*8+c2]
  const int bi = bh >> 3, h = bh & 7;
  float inv[2];
#pragma unroll
  for (int tm = 0; tm < 2; ++tm) {
    float l = rs[tm];
    l += __shfl_xor(l, 16, 64);
    l += __shfl_xor(l, 32, 64);
    inv[tm] = 1.f / l;
  }
#pragma unroll
  for (int ct = 0; ct < 4; ++ct)
#pragma unroll
    for (int tm = 0; tm < 2; ++tm) {
      const int n = qt * 256 + w * 32 + tm * 16 + l16;
      const int h2 = ct * 2 + (quad >> 1);          // (ct*16+quad*4)>>3
      const int c2b = (quad & 1) * 4;
      float4 v4;
      v4.x = O[ct][tm][0] * inv[tm]; v4.y = O[ct][tm][1] * inv[tm];
      v4.z = O[ct][tm][2] * inv[tm]; v4.w = O[ct][tm][3] * inv[tm];
      *reinterpret_cast<float4*>(
          &out[(((long)(bi * 8 + h2)) * NSEQ + n) * 64 + h * 8 + c2b]) = v4;
    }
}

extern "C" void kernel_launch(void* const* d_in, const int* in_sizes, int n_in,
                              void* d_out, int out_size, void* d_ws, size_t ws_size,
                              hipStream_t stream) {
  (void)in_sizes; (void)n_in; (void)out_size; (void)ws_size;
  const float* x = (const float*)d_in[0];   // [8,8,2048,64] fp32
  const float* w = (const float*)d_in[1];   // [192,64] fp32
  float* out = (float*)d_out;               // [8,8,2048,64] fp32

  // workspace: Q(scaled),K natural + Vt transposed, bf16 bits, 16.78 MB each
  ushort_t* qws  = (ushort_t*)d_ws;
  ushort_t* kws  = qws + (size_t)BH * NSEQ * CDIM;
  ushort_t* vtws = kws + (size_t)BH * NSEQ * CDIM;

  qkv_proj_mfma<<<(BH * NSEQ) / 128, 256, 0, stream>>>(x, w, qws, kws, vtws);
  flash_attn_mfma<<<512, 512, 0, stream>>>(qws, kws, vtws, out);
}